// Round 2
// baseline (383.967 us; speedup 1.0000x reference)
//
#include <hip/hip_runtime.h>

#define FUSE_K 20
#define NCH 16

// 2 voxels per thread (n0 and n0+half) to double memory-level parallelism.
// Phase 1: load both map rows. Phase 2: issue all 40 independent gathers
// into statically-indexed register arrays. Phase 3: reduce and store.
// c = gid & 15 keeps each 16-lane group's gather one contiguous 64 B segment.
__global__ __launch_bounds__(256) void VoxelPooling_kernel(
    const int* __restrict__ invoxel_map,   // (N, FUSE_K) int32
    const float* __restrict__ src_feat,    // (M, NCH) float32
    float* __restrict__ out,               // (N, NCH) float32
    int N)
{
    int half = (N + 1) >> 1;
    int gid = blockIdx.x * blockDim.x + threadIdx.x;
    int total = half * NCH;
    if (gid >= total) return;

    int c  = gid & 15;
    int n0 = gid >> 4;
    int n1 = n0 + half;
    bool has1 = (n1 < N);

    const int* m0 = invoxel_map + (size_t)n0 * FUSE_K;
    const int* m1 = invoxel_map + (size_t)(has1 ? n1 : n0) * FUSE_K;

    int i0[FUSE_K], i1[FUSE_K];
#pragma unroll
    for (int k = 0; k < FUSE_K; ++k) { i0[k] = m0[k]; i1[k] = m1[k]; }

    int f0 = i0[0], f1 = i1[0];

    float v0[FUSE_K], v1[FUSE_K];
#pragma unroll
    for (int k = 0; k < FUSE_K; ++k) {
        int a = (i0[k] == 0) ? f0 : i0[k];
        int b = (i1[k] == 0) ? f1 : i1[k];
        v0[k] = src_feat[(size_t)a * NCH + c];
        v1[k] = src_feat[(size_t)b * NCH + c];
    }

    float s0 = 0.0f, s1 = 0.0f;
#pragma unroll
    for (int k = 0; k < FUSE_K; ++k) { s0 += v0[k]; s1 += v1[k]; }

    out[(size_t)n0 * NCH + c] = s0 * (1.0f / FUSE_K);
    if (has1) out[(size_t)n1 * NCH + c] = s1 * (1.0f / FUSE_K);
}

extern "C" void kernel_launch(void* const* d_in, const int* in_sizes, int n_in,
                              void* d_out, int out_size, void* d_ws, size_t ws_size,
                              hipStream_t stream) {
    // d_in[0] = invoxel_xyz (unused)
    // d_in[1] = invoxel_map (int32), in_sizes[1] = N * FUSE_K
    // d_in[2] = src_feat    (float32)
    const int*   invoxel_map = (const int*)d_in[1];
    const float* src_feat    = (const float*)d_in[2];
    float*       out         = (float*)d_out;

    int N = in_sizes[1] / FUSE_K;
    int half = (N + 1) >> 1;
    int total = half * NCH;
    int block = 256;
    int grid = (total + block - 1) / block;

    VoxelPooling_kernel<<<grid, block, 0, stream>>>(invoxel_map, src_feat, out, N);
}

// Round 3
// 382.992 us; speedup vs baseline: 1.0025x; 1.0025x over previous
//
#include <hip/hip_runtime.h>

#define FUSE_K 20
#define NCH 16

// One thread per (voxel, 4-channel group): wave = 16 voxels x 4 lanes.
// Each gather is a global_load_dwordx4 -> 16 distinct 64B segments per wave
// per vmcnt slot (4x the MLP of dword gathers at equal instruction count).
// Map row (80 B, 16B-aligned) loads as 5 x int4; output is one float4 store.
__global__ __launch_bounds__(256) void VoxelPooling_kernel(
    const int* __restrict__ invoxel_map,    // (N, FUSE_K) int32
    const float4* __restrict__ src_feat4,   // (M, 4) float4  == (M,16) float
    float4* __restrict__ out4,              // (N, 4) float4  == (N,16) float
    int N)
{
    int gid = blockIdx.x * blockDim.x + threadIdx.x;
    if (gid >= N * 4) return;

    int n = gid >> 2;   // voxel
    int q = gid & 3;    // float4-group within the 16-channel row

    const int4* mrow = (const int4*)(invoxel_map + (size_t)n * FUSE_K);

    int idx[FUSE_K];
#pragma unroll
    for (int k = 0; k < FUSE_K / 4; ++k) {
        int4 t = mrow[k];
        idx[4 * k + 0] = t.x;
        idx[4 * k + 1] = t.y;
        idx[4 * k + 2] = t.z;
        idx[4 * k + 3] = t.w;
    }

    int first = idx[0];

    float4 v[FUSE_K];
#pragma unroll
    for (int k = 0; k < FUSE_K; ++k) {
        int a = (idx[k] == 0) ? first : idx[k];
        v[k] = src_feat4[(size_t)a * 4 + q];
    }

    float sx = 0.f, sy = 0.f, sz = 0.f, sw = 0.f;
#pragma unroll
    for (int k = 0; k < FUSE_K; ++k) {
        sx += v[k].x; sy += v[k].y; sz += v[k].z; sw += v[k].w;
    }

    float4 r;
    r.x = sx * (1.0f / FUSE_K);
    r.y = sy * (1.0f / FUSE_K);
    r.z = sz * (1.0f / FUSE_K);
    r.w = sw * (1.0f / FUSE_K);
    out4[gid] = r;
}

extern "C" void kernel_launch(void* const* d_in, const int* in_sizes, int n_in,
                              void* d_out, int out_size, void* d_ws, size_t ws_size,
                              hipStream_t stream) {
    // d_in[0] = invoxel_xyz (unused)
    // d_in[1] = invoxel_map (int32), in_sizes[1] = N * FUSE_K
    // d_in[2] = src_feat    (float32, M x 16)
    const int*    invoxel_map = (const int*)d_in[1];
    const float4* src_feat4   = (const float4*)d_in[2];
    float4*       out4        = (float4*)d_out;

    int N = in_sizes[1] / FUSE_K;
    int total = N * 4;
    int block = 256;
    int grid = (total + block - 1) / block;

    VoxelPooling_kernel<<<grid, block, 0, stream>>>(invoxel_map, src_feat4, out4, N);
}

// Round 4
// 382.147 us; speedup vs baseline: 1.0048x; 1.0022x over previous
//
#include <hip/hip_runtime.h>

#define FUSE_K 20
#define NCH 16

typedef float f32x4 __attribute__((ext_vector_type(4)));

// Forced-MLP probe/kernel: all 20 dwordx4 gathers issued as opaque inline-asm
// loads (compiler cannot re-fuse into load->wait->add batches), one manual
// s_waitcnt vmcnt(0), sched_barrier(0) per guide rule #18, then reduce.
// Thread = (voxel, 4-channel group); wave = 16 voxels x 4 lanes, so each
// wave-gather covers 16 distinct 64 B rows.
__global__ __launch_bounds__(256) void VoxelPooling_kernel(
    const int* __restrict__ invoxel_map,    // (N, FUSE_K) int32
    const f32x4* __restrict__ src_feat4,    // (M,16) float == (M,4) float4
    f32x4* __restrict__ out4,               // (N,16) float == (N,4) float4
    int N)
{
    int gid = blockIdx.x * blockDim.x + threadIdx.x;
    if (gid >= N * 4) return;

    int n = gid >> 2;   // voxel
    int q = gid & 3;    // float4-group within the 16-channel row

    const int4* mrow = (const int4*)(invoxel_map + (size_t)n * FUSE_K);

    int idx[FUSE_K];
#pragma unroll
    for (int k = 0; k < FUSE_K / 4; ++k) {
        int4 t = mrow[k];
        idx[4 * k + 0] = t.x;
        idx[4 * k + 1] = t.y;
        idx[4 * k + 2] = t.z;
        idx[4 * k + 3] = t.w;
    }

    int first = idx[0];

    f32x4 v[FUSE_K];
#pragma unroll
    for (int k = 0; k < FUSE_K; ++k) {
        int a = (idx[k] == 0) ? first : idx[k];
        const f32x4* p = src_feat4 + (size_t)a * 4 + q;
        // Opaque async load: dest stays live until the explicit waitcnt.
        asm volatile("global_load_dwordx4 %0, %1, off"
                     : "=v"(v[k])
                     : "v"(p));
    }

    // Wait for all 20 gathers, then fence the scheduler so no consumer add
    // is hoisted above the waitcnt (register-only ops ignore "memory").
    asm volatile("s_waitcnt vmcnt(0)" ::: "memory");
    __builtin_amdgcn_sched_barrier(0);

    float sx = 0.f, sy = 0.f, sz = 0.f, sw = 0.f;
#pragma unroll
    for (int k = 0; k < FUSE_K; ++k) {
        sx += v[k].x; sy += v[k].y; sz += v[k].z; sw += v[k].w;
    }

    f32x4 r;
    r.x = sx * (1.0f / FUSE_K);
    r.y = sy * (1.0f / FUSE_K);
    r.z = sz * (1.0f / FUSE_K);
    r.w = sw * (1.0f / FUSE_K);
    out4[gid] = r;
}

extern "C" void kernel_launch(void* const* d_in, const int* in_sizes, int n_in,
                              void* d_out, int out_size, void* d_ws, size_t ws_size,
                              hipStream_t stream) {
    // d_in[0] = invoxel_xyz (unused)
    // d_in[1] = invoxel_map (int32), in_sizes[1] = N * FUSE_K
    // d_in[2] = src_feat    (float32, M x 16)
    const int*   invoxel_map = (const int*)d_in[1];
    const f32x4* src_feat4   = (const f32x4*)d_in[2];
    f32x4*       out4        = (f32x4*)d_out;

    int N = in_sizes[1] / FUSE_K;
    int total = N * 4;
    int block = 256;
    int grid = (total + block - 1) / block;

    VoxelPooling_kernel<<<grid, block, 0, stream>>>(invoxel_map, src_feat4, out4, N);
}